// Round 4
// baseline (230.803 us; speedup 1.0000x reference)
//
#include <hip/hip_runtime.h>

// TriggerAwareGAT fused pipeline for MI355X (gfx950).
// k1: trigger MLPs (temp, gate, stb_eff, c_trig)    [1 x 128]
// k2: h = relu(LN1(enriched@Wp^T+bp))               [4096 x 128]
// k3: Q,K (fp16, scale folded into Q), V^T (fp16)   [128x3 x 256]
// k4: flash masked attention, fp16 MFMA, 32 rows/blk, j-split=4 [128x4 x 256]
// k5: combine partials, Wo GEMM (k-split staging), LN2, residual [256 x 256]

#define NNODES 4096
#define BI     32                    // i-rows per k4 block
#define JSPLIT 4
#define JCHUNK (NNODES / JSPLIT)     // 1024
#define NT     (JCHUNK / 32)         // 32

typedef float    f32x4 __attribute__((ext_vector_type(4)));
typedef _Float16 f16x8 __attribute__((ext_vector_type(8)));
typedef __fp16   fp16x2 __attribute__((ext_vector_type(2)));

// workspace layout (float offsets)
#define P_PARAMS 0
#define P_STF    256
#define P_H      4352
#define P_QH     528640
#define P_KH     790784
#define P_VT     1052928
#define P_PAGG   1315072  // [JSPLIT*4][4096][32] f32
#define P_PML    3412224  // [JSPLIT*4][4096][2]  f32
// params sub-offsets
#define PP_SCALE 0
#define PP_STB2  4
#define PP_GATE  8
#define PP_CTRIG 16

__device__ __forceinline__ unsigned pk_f16(float lo, float hi) {
  union { fp16x2 h; unsigned u; } c;
  c.h = __builtin_amdgcn_cvt_pkrtz(lo, hi);
  return c.u;
}

// ---------------- k1: trigger-side tiny MLPs ----------------
__global__ __launch_bounds__(128) void k1_trigger(
    const float* __restrict__ trig,
    const float* __restrict__ Wp, const float* __restrict__ bp,
    const float* __restrict__ Wt1, const float* __restrict__ bt1,
    const float* __restrict__ Wt2, const float* __restrict__ bt2,
    const float* __restrict__ Wg, const float* __restrict__ bg,
    const float* __restrict__ stb,
    float* __restrict__ ws)
{
  __shared__ float s_t1[64];
  __shared__ float s_red[2];
  const int t = threadIdx.x;  // 128 threads
  const float t0 = trig[0], t1v = trig[1], t2 = trig[2];

  // c_trig[j] = bp[j] + trig . Wp[j][3:6]
  ws[P_PARAMS + PP_CTRIG + t] = bp[t] + t0 * Wp[t*6+3] + t1v * Wp[t*6+4] + t2 * Wp[t*6+5];

  if (t < 64) {
    float a = bt1[t] + t0 * Wt1[t*3+0] + t1v * Wt1[t*3+1] + t2 * Wt1[t*3+2];
    s_t1[t] = fmaxf(a, 0.f);
  }
  // gate = mean(sigmoid(Wg@trig + bg))
  float gx = bg[t] + t0 * Wg[t*3+0] + t1v * Wg[t*3+1] + t2 * Wg[t*3+2];
  float gs = 1.f / (1.f + __expf(-gx));
  for (int off = 1; off < 64; off <<= 1) gs += __shfl_xor(gs, off);
  if ((t & 63) == 0) s_red[t >> 6] = gs;
  __syncthreads();
  if (t == 0) ws[P_PARAMS + PP_GATE] = (s_red[0] + s_red[1]) * (1.f / 128.f);
  if (t < 4) {
    float acc = bt2[t];
    for (int k = 0; k < 64; ++k) acc += Wt2[t*64+k] * s_t1[k];
    float sp = (acc > 20.f) ? acc : log1pf(__expf(acc));
    float temp = fminf(fmaxf(sp, 0.1f), 5.f);
    const float LOG2E = 1.4426950408889634f;
    ws[P_PARAMS + PP_SCALE + t] = LOG2E / (5.656854249492380f * temp); // log2e/(sqrt(32)*temp)
    ws[P_PARAMS + PP_STB2  + t] = stb[t] * (1.f - t0) * LOG2E;
  }
}

// ---------------- k2: h = relu(LN1(enriched@Wp^T + bp)) ----------------
__global__ __launch_bounds__(128) void k2_h(
    const float* __restrict__ nf, const float* __restrict__ Wp,
    const float* __restrict__ g, const float* __restrict__ b,
    float* __restrict__ ws)
{
  const int i = blockIdx.x, j = threadIdx.x; // 128 threads / row
  const float* ctrig = ws + P_PARAMS + PP_CTRIG;
  const float n0 = nf[i*3+0], n1 = nf[i*3+1], n2 = nf[i*3+2];
  const float x = ctrig[j] + n0 * Wp[j*6+0] + n1 * Wp[j*6+1] + n2 * Wp[j*6+2];
  float s = x, sq = x * x;
  for (int off = 1; off < 64; off <<= 1) { s += __shfl_xor(s, off); sq += __shfl_xor(sq, off); }
  __shared__ float red[2][2];
  if ((j & 63) == 0) { red[j >> 6][0] = s; red[j >> 6][1] = sq; }
  __syncthreads();
  const float mu = (red[0][0] + red[1][0]) * (1.f / 128.f);
  const float var = (red[0][1] + red[1][1]) * (1.f / 128.f) - mu * mu;
  const float rs = rsqrtf(var + 1e-5f);
  const float hv = fmaxf((x - mu) * rs * g[j] + b[j], 0.f);
  ws[P_H + (size_t)i * 128 + j] = hv;
  if (j == 0) ws[P_STF + i] = n2;   // is_stateful
}

// ---------------- k3: QKV GEMMs -> fp16 Q (scaled), K, V^T ----------------
__global__ __launch_bounds__(256) void k3_qkv(
    const float* __restrict__ Wq, const float* __restrict__ Wk,
    const float* __restrict__ Wv, float* __restrict__ ws)
{
  __shared__ float h_s[32][129];
  __shared__ float w_s[32][128];   // W^T chunk [k][c]
  __shared__ float o_s[32][132];   // V transpose buffer
  const int t = threadIdx.x;
  const int r0 = blockIdx.x * 32;
  const int mat = blockIdx.y;
  const float* W = (mat == 0) ? Wq : (mat == 1) ? Wk : Wv;
  const float* hp = ws + P_H;

  { // stage h tile
    const int r = t >> 3, kb = (t & 7) << 4;
    const float4* src = (const float4*)(hp + (size_t)(r0 + r) * 128 + kb);
#pragma unroll
    for (int p = 0; p < 4; ++p) {
      float4 v = src[p];
      h_s[r][kb + 4*p + 0] = v.x; h_s[r][kb + 4*p + 1] = v.y;
      h_s[r][kb + 4*p + 2] = v.z; h_s[r][kb + 4*p + 3] = v.w;
    }
  }

  const int rr = t & 31, cs = (t >> 5) << 4;
  float acc[16];
#pragma unroll
  for (int e = 0; e < 16; ++e) acc[e] = 0.f;

  for (int kc = 0; kc < 4; ++kc) {
    __syncthreads();
    { // stage W^T chunk (transposed in LDS so compute reads are conflict-free)
      const int c = t >> 1, kk = (t & 1) << 4;
      const float4* srcw = (const float4*)(W + c * 128 + kc * 32 + kk);
#pragma unroll
      for (int p = 0; p < 4; ++p) {
        float4 v = srcw[p];
        w_s[kk + 4*p + 0][c] = v.x; w_s[kk + 4*p + 1][c] = v.y;
        w_s[kk + 4*p + 2][c] = v.z; w_s[kk + 4*p + 3][c] = v.w;
      }
    }
    __syncthreads();
#pragma unroll
    for (int k = 0; k < 32; ++k) {
      const float a = h_s[rr][kc * 32 + k];
      const float4 w0 = *(const float4*)&w_s[k][cs + 0];
      const float4 w1 = *(const float4*)&w_s[k][cs + 4];
      const float4 w2 = *(const float4*)&w_s[k][cs + 8];
      const float4 w3 = *(const float4*)&w_s[k][cs + 12];
      acc[0]  += a * w0.x; acc[1]  += a * w0.y; acc[2]  += a * w0.z; acc[3]  += a * w0.w;
      acc[4]  += a * w1.x; acc[5]  += a * w1.y; acc[6]  += a * w1.z; acc[7]  += a * w1.w;
      acc[8]  += a * w2.x; acc[9]  += a * w2.y; acc[10] += a * w2.z; acc[11] += a * w2.w;
      acc[12] += a * w3.x; acc[13] += a * w3.y; acc[14] += a * w3.z; acc[15] += a * w3.w;
    }
  }

  const float* params = ws + P_PARAMS;
  if (mat < 2) {
    unsigned short* dst = (unsigned short*)(ws + (mat == 0 ? P_QH : P_KH));
    const float sc = (mat == 0) ? params[PP_SCALE + (cs >> 5)] : 1.f;
    uint4 w0, w1;
    w0.x = pk_f16(acc[0]*sc,  acc[1]*sc);  w0.y = pk_f16(acc[2]*sc,  acc[3]*sc);
    w0.z = pk_f16(acc[4]*sc,  acc[5]*sc);  w0.w = pk_f16(acc[6]*sc,  acc[7]*sc);
    w1.x = pk_f16(acc[8]*sc,  acc[9]*sc);  w1.y = pk_f16(acc[10]*sc, acc[11]*sc);
    w1.z = pk_f16(acc[12]*sc, acc[13]*sc); w1.w = pk_f16(acc[14]*sc, acc[15]*sc);
    *(uint4*)(dst + (size_t)(r0 + rr) * 128 + cs)     = w0;
    *(uint4*)(dst + (size_t)(r0 + rr) * 128 + cs + 8) = w1;
  } else {
#pragma unroll
    for (int e = 0; e < 16; ++e) o_s[rr][cs + e] = acc[e];
    __syncthreads();
    unsigned short* vt = (unsigned short*)(ws + P_VT);
    const int c = t >> 1, rb = (t & 1) << 4;
    float v[16];
#pragma unroll
    for (int mm = 0; mm < 16; ++mm) v[mm] = o_s[rb + mm][c];
    uint4 w0, w1;
    w0.x = pk_f16(v[0],  v[1]);  w0.y = pk_f16(v[2],  v[3]);
    w0.z = pk_f16(v[4],  v[5]);  w0.w = pk_f16(v[6],  v[7]);
    w1.x = pk_f16(v[8],  v[9]);  w1.y = pk_f16(v[10], v[11]);
    w1.z = pk_f16(v[12], v[13]); w1.w = pk_f16(v[14], v[15]);
    *(uint4*)(vt + (size_t)c * 4096 + r0 + rb)     = w0;
    *(uint4*)(vt + (size_t)c * 4096 + r0 + rb + 8) = w1;
  }
}

// ---------------- k4: fused masked flash attention (fp16 MFMA) ----------------
// wave w = head w; 32 i-rows/block (2 MFMA i-tiles); V/K frags shared across i-tiles.
// S computed transposed: S^T = mfma(K,Q); PV via k-axis relabeling (no shuffles).
__global__ __launch_bounds__(256) void k4_attn(
    const float* __restrict__ adj, float* __restrict__ ws)
{
  __shared__ float adj_s[2][BI][36];  // padded
  const int tid = threadIdx.x;
  const int w = tid >> 6, l = tid & 63, li = l & 15, g = l >> 4;
  const int i0 = blockIdx.x * BI;
  const int jbeg = blockIdx.y * JCHUNK;
  const _Float16* Qh = (const _Float16*)(ws + P_QH);
  const _Float16* Kh = (const _Float16*)(ws + P_KH);
  const _Float16* VT = (const _Float16*)(ws + P_VT);
  const float* stf = ws + P_STF;
  const float* params = ws + P_PARAMS;

  f16x8 qf[2];
  float a_stb[2], m[2], lsum[2];
  f32x4 agg[2][2];
#pragma unroll
  for (int it = 0; it < 2; ++it) {
    qf[it] = *(const f16x8*)(Qh + (size_t)(i0 + it*16 + li) * 128 + w * 32 + g * 8);
    a_stb[it] = stf[i0 + it*16 + li] * params[PP_STB2 + w];
    m[it] = -1e30f; lsum[it] = 0.f;
    agg[it][0] = (f32x4){0.f, 0.f, 0.f, 0.f};
    agg[it][1] = (f32x4){0.f, 0.f, 0.f, 0.f};
  }

  const int sr = tid >> 3, sjb = (tid & 7) << 2;   // 32 rows x 8 float4
  const float* adj_base = adj + (size_t)(i0 + sr) * 4096 + jbeg + sjb;
  f32x4 reg = __builtin_nontemporal_load((const f32x4*)adj_base);
  *(f32x4*)&adj_s[0][sr][sjb] = reg;

  for (int t = 0; t < NT; ++t) {
    if (t + 1 < NT)
      reg = __builtin_nontemporal_load((const f32x4*)(adj_base + (t + 1) * 32));
    __syncthreads();
    const int buf = t & 1;
    const int jt = jbeg + t * 32;

    const f16x8 kf0 = *(const f16x8*)(Kh + (size_t)(jt + li) * 128 + w * 32 + g * 8);
    const f16x8 kf1 = *(const f16x8*)(Kh + (size_t)(jt + 16 + li) * 128 + w * 32 + g * 8);

    // V^T frags (shared across both i-tiles); k-slot (g,e) <-> j = (e<4 ? 4g+e : 16+4g+e-4)
    union { unsigned u[4]; f16x8 h; } vf0, vf1;
    {
      const _Float16* vr0 = VT + (size_t)(w * 32 + li) * 4096 + jt + g * 4;
      uint2 va = *(const uint2*)vr0;
      uint2 vb = *(const uint2*)(vr0 + 16);
      vf0.u[0] = va.x; vf0.u[1] = va.y; vf0.u[2] = vb.x; vf0.u[3] = vb.y;
      const _Float16* vr1 = vr0 + 16 * 4096;
      uint2 vc = *(const uint2*)vr1;
      uint2 vd = *(const uint2*)(vr1 + 16);
      vf1.u[0] = vc.x; vf1.u[1] = vc.y; vf1.u[2] = vd.x; vf1.u[3] = vd.y;
    }

    const f32x4 st0 = *(const f32x4*)(stf + jt + g * 4);
    const f32x4 st1 = *(const f32x4*)(stf + jt + 16 + g * 4);

#pragma unroll
    for (int it = 0; it < 2; ++it) {
      const f32x4 zero = {0.f, 0.f, 0.f, 0.f};
      f32x4 c0 = __builtin_amdgcn_mfma_f32_16x16x32_f16(kf0, qf[it], zero, 0, 0, 0);
      f32x4 c1 = __builtin_amdgcn_mfma_f32_16x16x32_f16(kf1, qf[it], zero, 0, 0, 0);

      const f32x4 ad0 = *(const f32x4*)&adj_s[buf][it*16 + li][g * 4];
      const f32x4 ad1 = *(const f32x4*)&adj_s[buf][it*16 + li][16 + g * 4];

      float s0[4], s1[4];
#pragma unroll
      for (int e = 0; e < 4; ++e) {
        s0[e] = ((ad0[e] == 0.f) ? -1e9f : c0[e]) + a_stb[it] * st0[e];
        s1[e] = ((ad1[e] == 0.f) ? -1e9f : c1[e]) + a_stb[it] * st1[e];
      }

      float mx = fmaxf(fmaxf(fmaxf(s0[0], s0[1]), fmaxf(s0[2], s0[3])),
                       fmaxf(fmaxf(s1[0], s1[1]), fmaxf(s1[2], s1[3])));
      mx = fmaxf(mx, __shfl_xor(mx, 16));
      mx = fmaxf(mx, __shfl_xor(mx, 32));
      const float mn = fmaxf(m[it], mx);
      const float f = exp2f(m[it] - mn);
      float p0[4], p1[4];
#pragma unroll
      for (int e = 0; e < 4; ++e) { p0[e] = exp2f(s0[e] - mn); p1[e] = exp2f(s1[e] - mn); }
      float ts = ((p0[0] + p0[1]) + (p0[2] + p0[3])) + ((p1[0] + p1[1]) + (p1[2] + p1[3]));
      ts += __shfl_xor(ts, 16);
      ts += __shfl_xor(ts, 32);
      lsum[it] = lsum[it] * f + ts;
      m[it] = mn;
#pragma unroll
      for (int e = 0; e < 4; ++e) { agg[it][0][e] *= f; agg[it][1][e] *= f; }

      union { unsigned u[4]; f16x8 h; } pb;
      pb.u[0] = pk_f16(p0[0], p0[1]);
      pb.u[1] = pk_f16(p0[2], p0[3]);
      pb.u[2] = pk_f16(p1[0], p1[1]);
      pb.u[3] = pk_f16(p1[2], p1[3]);

      agg[it][0] = __builtin_amdgcn_mfma_f32_16x16x32_f16(vf0.h, pb.h, agg[it][0], 0, 0, 0);
      agg[it][1] = __builtin_amdgcn_mfma_f32_16x16x32_f16(vf1.h, pb.h, agg[it][1], 0, 0, 0);
    }

    if (t + 1 < NT)
      *(f32x4*)&adj_s[(t + 1) & 1][sr][sjb] = reg;
  }

  // partials: agg^T lane layout: d_local = 16*db + 4g + e, i = i0 + it*16 + li
#pragma unroll
  for (int it = 0; it < 2; ++it) {
    float* pagg = ws + P_PAGG + ((size_t)(blockIdx.y * 4 + w) * 4096 + (i0 + it*16 + li)) * 32;
    *(f32x4*)(pagg + g * 4)      = agg[it][0];
    *(f32x4*)(pagg + 16 + g * 4) = agg[it][1];
    if (g == 0) {
      float* pml = ws + P_PML + ((size_t)(blockIdx.y * 4 + w) * 4096 + (i0 + it*16 + li)) * 2;
      pml[0] = m[it];
      pml[1] = lsum[it];
    }
  }
}

// ---------------- k5: combine + Wo GEMM (k-split staging) + LN2 + residual ----------------
__global__ __launch_bounds__(256) void k5_out(
    const float* __restrict__ Wo, const float* __restrict__ bo,
    const float* __restrict__ g2, const float* __restrict__ b2,
    const float* __restrict__ res_scale,
    float* __restrict__ ws, float* __restrict__ out)
{
  __shared__ float wo_s[64][128];  // Wo^T half: [k][c], staged twice (32 KB)
  __shared__ float agg_s[16][132];
  __shared__ float red[16][16][2];
  __shared__ float mu_s[16], rs_s[16];
  const int t = threadIdx.x;
  const int i0 = blockIdx.x * 16;

  { // combine j-split partials -> agg_s (gate * sum(pV)/l)
    const float gate = ws[P_PARAMS + PP_GATE];
    const int hd = t & 127, ih = t >> 7;
    const int h = hd >> 5, d = hd & 31;
    for (int ir = 0; ir < 8; ++ir) {
      const int il = ih * 8 + ir;
      const int i = i0 + il;
      float mv[JSPLIT], lv[JSPLIT];
      float mm = -1e30f;
#pragma unroll
      for (int sp = 0; sp < JSPLIT; ++sp) {
        const float* ml = ws + P_PML + ((size_t)(sp * 4 + h) * 4096 + i) * 2;
        mv[sp] = ml[0]; lv[sp] = ml[1];
        mm = fmaxf(mm, mv[sp]);
      }
      float lt = 0.f, av = 0.f;
#pragma unroll
      for (int sp = 0; sp < JSPLIT; ++sp) {
        const float wgt = exp2f(mv[sp] - mm);
        lt += lv[sp] * wgt;
        av += ws[P_PAGG + ((size_t)(sp * 4 + h) * 4096 + i) * 32 + d] * wgt;
      }
      agg_s[il][hd] = av * gate / lt;
    }
  }

  const int r = t & 15, cs = (t >> 4) << 3;
  float acc[8];
#pragma unroll
  for (int e = 0; e < 8; ++e) acc[e] = bo[cs + e];

  for (int kh = 0; kh < 2; ++kh) {
    __syncthreads();   // protect wo_s reuse (and covers agg_s on first pass)
    { // stage Wo^T[kh*64 + kk][c] into wo_s[kk][c]
      const int c = t >> 1, kb = (t & 1) << 5;  // two 32-float chunks per row
      const float4* src = (const float4*)(Wo + c * 128 + kh * 64 + kb);
#pragma unroll
      for (int q = 0; q < 8; ++q) {
        float4 v = src[q];
        wo_s[kb + 4*q + 0][c] = v.x; wo_s[kb + 4*q + 1][c] = v.y;
        wo_s[kb + 4*q + 2][c] = v.z; wo_s[kb + 4*q + 3][c] = v.w;
      }
    }
    __syncthreads();
    for (int k = 0; k < 64; ++k) {
      const float a = agg_s[r][kh * 64 + k];
      const float4 w0 = *(const float4*)&wo_s[k][cs];
      const float4 w1 = *(const float4*)&wo_s[k][cs + 4];
      acc[0] += a * w0.x; acc[1] += a * w0.y; acc[2] += a * w0.z; acc[3] += a * w0.w;
      acc[4] += a * w1.x; acc[5] += a * w1.y; acc[6] += a * w1.z; acc[7] += a * w1.w;
    }
  }

  float s = 0.f, sq = 0.f;
#pragma unroll
  for (int e = 0; e < 8; ++e) { s += acc[e]; sq += acc[e] * acc[e]; }
  red[r][t >> 4][0] = s; red[r][t >> 4][1] = sq;
  __syncthreads();
  if (t < 16) {
    float ss = 0.f, qq = 0.f;
    for (int q = 0; q < 16; ++q) { ss += red[t][q][0]; qq += red[t][q][1]; }
    const float mu = ss * (1.f / 128.f);
    const float var = qq * (1.f / 128.f) - mu * mu;
    mu_s[t] = mu; rs_s[t] = rsqrtf(var + 1e-5f);
  }
  __syncthreads();
  const float mu = mu_s[r], rs = rs_s[r];
  const float rsc = res_scale[0];
  const float* hrow = ws + P_H + (size_t)(i0 + r) * 128 + cs;
  const float4 h0 = *(const float4*)(hrow), h1 = *(const float4*)(hrow + 4);
  const float4 ga = *(const float4*)(g2 + cs), gb = *(const float4*)(g2 + cs + 4);
  const float4 ba = *(const float4*)(b2 + cs), bb = *(const float4*)(b2 + cs + 4);
  float4 o0, o1;
  o0.x = (acc[0] - mu) * rs * ga.x + ba.x + rsc * h0.x;
  o0.y = (acc[1] - mu) * rs * ga.y + ba.y + rsc * h0.y;
  o0.z = (acc[2] - mu) * rs * ga.z + ba.z + rsc * h0.z;
  o0.w = (acc[3] - mu) * rs * ga.w + ba.w + rsc * h0.w;
  o1.x = (acc[4] - mu) * rs * gb.x + bb.x + rsc * h1.x;
  o1.y = (acc[5] - mu) * rs * gb.y + bb.y + rsc * h1.y;
  o1.z = (acc[6] - mu) * rs * gb.z + bb.z + rsc * h1.z;
  o1.w = (acc[7] - mu) * rs * gb.w + bb.w + rsc * h1.w;
  *(float4*)(out + (size_t)(i0 + r) * 128 + cs)     = o0;
  *(float4*)(out + (size_t)(i0 + r) * 128 + cs + 4) = o1;
}

extern "C" void kernel_launch(void* const* d_in, const int* in_sizes, int n_in,
                              void* d_out, int out_size, void* d_ws, size_t ws_size,
                              hipStream_t stream) {
  const float* nf   = (const float*)d_in[0];
  const float* adj  = (const float*)d_in[1];
  const float* trig = (const float*)d_in[2];
  const float* Wp   = (const float*)d_in[3];
  const float* bp   = (const float*)d_in[4];
  const float* ln1g = (const float*)d_in[5];
  const float* ln1b = (const float*)d_in[6];
  const float* Wq   = (const float*)d_in[7];
  const float* Wk   = (const float*)d_in[8];
  const float* Wv   = (const float*)d_in[9];
  const float* Wt1  = (const float*)d_in[10];
  const float* bt1  = (const float*)d_in[11];
  const float* Wt2  = (const float*)d_in[12];
  const float* bt2  = (const float*)d_in[13];
  const float* Wg   = (const float*)d_in[14];
  const float* bg   = (const float*)d_in[15];
  const float* stb  = (const float*)d_in[16];
  const float* Wo   = (const float*)d_in[17];
  const float* bo   = (const float*)d_in[18];
  const float* ln2g = (const float*)d_in[19];
  const float* ln2b = (const float*)d_in[20];
  const float* rsc  = (const float*)d_in[21];
  float* ws  = (float*)d_ws;
  float* out = (float*)d_out;

  hipLaunchKernelGGL(k1_trigger, dim3(1), dim3(128), 0, stream,
                     trig, Wp, bp, Wt1, bt1, Wt2, bt2, Wg, bg, stb, ws);
  hipLaunchKernelGGL(k2_h, dim3(NNODES), dim3(128), 0, stream, nf, Wp, ln1g, ln1b, ws);
  hipLaunchKernelGGL(k3_qkv, dim3(128, 3), dim3(256), 0, stream, Wq, Wk, Wv, ws);
  hipLaunchKernelGGL(k4_attn, dim3(NNODES / BI, JSPLIT), dim3(256), 0, stream, adj, ws);
  hipLaunchKernelGGL(k5_out, dim3(256), dim3(256), 0, stream, Wo, bo, ln2g, ln2b, rsc, ws, out);
}

// Round 5
// 228.751 us; speedup vs baseline: 1.0090x; 1.0090x over previous
//
#include <hip/hip_runtime.h>

// TriggerAwareGAT fused pipeline for MI355X (gfx950).
// k2: h = relu(LN1(enriched@Wp^T+bp)) + inline c_trig        [4096 x 128]
// k3: Q,K (fp16, scale folded into Q), V^T (fp16) + temp MLP [128x3 x 256]
// k4: flash masked attention, fp16 MFMA, pipelined loads,
//     exact defer-max, per-lane lsum, j-split=8               [128x8 x 256]
// k5: combine partials + inline gate, Wo GEMM, LN2, residual  [256 x 256]

#define NNODES 4096
#define BI     32                    // i-rows per k4 block
#define JSPLIT 8
#define JCHUNK (NNODES / JSPLIT)     // 512
#define NT     (JCHUNK / 32)         // 16

typedef float    f32x4 __attribute__((ext_vector_type(4)));
typedef _Float16 f16x8 __attribute__((ext_vector_type(8)));
typedef __fp16   fp16x2 __attribute__((ext_vector_type(2)));

// workspace layout (float offsets)
#define P_STF    256
#define P_H      4352
#define P_QH     528640
#define P_KH     790784
#define P_VT     1052928
#define P_PAGG   1315072  // [JSPLIT*4][4096][32] f32
#define P_PML    5509376  // [JSPLIT*4][4096][2]  f32

#define LOG2E 1.4426950408889634f

__device__ __forceinline__ unsigned pk_f16(float lo, float hi) {
  union { fp16x2 h; unsigned u; } c;
  c.h = __builtin_amdgcn_cvt_pkrtz(lo, hi);
  return c.u;
}

// ---------------- k2: h = relu(LN1(enriched@Wp^T + bp)) ----------------
__global__ __launch_bounds__(128) void k2_h(
    const float* __restrict__ nf, const float* __restrict__ trig,
    const float* __restrict__ Wp, const float* __restrict__ bp,
    const float* __restrict__ g, const float* __restrict__ b,
    float* __restrict__ ws)
{
  const int i = blockIdx.x, j = threadIdx.x; // 128 threads / row
  const float t0 = trig[0], t1v = trig[1], t2 = trig[2];
  const float n0 = nf[i*3+0], n1 = nf[i*3+1], n2 = nf[i*3+2];
  const float* wr = Wp + j * 6;
  const float x = bp[j] + n0 * wr[0] + n1 * wr[1] + n2 * wr[2]
                        + t0 * wr[3] + t1v * wr[4] + t2 * wr[5];
  float s = x, sq = x * x;
  for (int off = 1; off < 64; off <<= 1) { s += __shfl_xor(s, off); sq += __shfl_xor(sq, off); }
  __shared__ float red[2][2];
  if ((j & 63) == 0) { red[j >> 6][0] = s; red[j >> 6][1] = sq; }
  __syncthreads();
  const float mu = (red[0][0] + red[1][0]) * (1.f / 128.f);
  const float var = (red[0][1] + red[1][1]) * (1.f / 128.f) - mu * mu;
  const float rs = rsqrtf(var + 1e-5f);
  const float hv = fmaxf((x - mu) * rs * g[j] + b[j], 0.f);
  ws[P_H + (size_t)i * 128 + j] = hv;
  if (j == 0) ws[P_STF + i] = n2;   // is_stateful
}

// ---------------- k3: QKV GEMMs -> fp16 Q (scaled), K, V^T ----------------
__global__ __launch_bounds__(256) void k3_qkv(
    const float* __restrict__ Wq, const float* __restrict__ Wk,
    const float* __restrict__ Wv, const float* __restrict__ trig,
    const float* __restrict__ Wt1, const float* __restrict__ bt1,
    const float* __restrict__ Wt2, const float* __restrict__ bt2,
    float* __restrict__ ws)
{
  __shared__ float h_s[32][129];
  __shared__ float w_s[32][128];   // W^T chunk [k][c]
  __shared__ float o_s[32][132];   // V transpose buffer
  __shared__ float t1_s[64];
  __shared__ float scale_s[4];
  const int t = threadIdx.x;
  const int r0 = blockIdx.x * 32;
  const int mat = blockIdx.y;
  const float* W = (mat == 0) ? Wq : (mat == 1) ? Wk : Wv;
  const float* hp = ws + P_H;

  { // stage h tile
    const int r = t >> 3, kb = (t & 7) << 4;
    const float4* src = (const float4*)(hp + (size_t)(r0 + r) * 128 + kb);
#pragma unroll
    for (int p = 0; p < 4; ++p) {
      float4 v = src[p];
      h_s[r][kb + 4*p + 0] = v.x; h_s[r][kb + 4*p + 1] = v.y;
      h_s[r][kb + 4*p + 2] = v.z; h_s[r][kb + 4*p + 3] = v.w;
    }
  }
  if (t < 64) { // trigger hidden layer (for temp/scale, used by mat==0 only)
    float a = bt1[t] + trig[0] * Wt1[t*3+0] + trig[1] * Wt1[t*3+1] + trig[2] * Wt1[t*3+2];
    t1_s[t] = fmaxf(a, 0.f);
  }
  __syncthreads();
  if (t < 4) {
    float acc = bt2[t];
    for (int k = 0; k < 64; ++k) acc += Wt2[t*64+k] * t1_s[k];
    float sp = (acc > 20.f) ? acc : log1pf(__expf(acc));
    float temp = fminf(fmaxf(sp, 0.1f), 5.f);
    scale_s[t] = LOG2E / (5.656854249492380f * temp); // log2e/(sqrt(32)*temp)
  }

  const int rr = t & 31, cs = (t >> 5) << 4;
  float acc[16];
#pragma unroll
  for (int e = 0; e < 16; ++e) acc[e] = 0.f;

  for (int kc = 0; kc < 4; ++kc) {
    __syncthreads();
    { // stage W^T chunk (transposed in LDS so compute reads are conflict-free)
      const int c = t >> 1, kk = (t & 1) << 4;
      const float4* srcw = (const float4*)(W + c * 128 + kc * 32 + kk);
#pragma unroll
      for (int p = 0; p < 4; ++p) {
        float4 v = srcw[p];
        w_s[kk + 4*p + 0][c] = v.x; w_s[kk + 4*p + 1][c] = v.y;
        w_s[kk + 4*p + 2][c] = v.z; w_s[kk + 4*p + 3][c] = v.w;
      }
    }
    __syncthreads();
#pragma unroll
    for (int k = 0; k < 32; ++k) {
      const float a = h_s[rr][kc * 32 + k];
      const float4 w0 = *(const float4*)&w_s[k][cs + 0];
      const float4 w1 = *(const float4*)&w_s[k][cs + 4];
      const float4 w2 = *(const float4*)&w_s[k][cs + 8];
      const float4 w3 = *(const float4*)&w_s[k][cs + 12];
      acc[0]  += a * w0.x; acc[1]  += a * w0.y; acc[2]  += a * w0.z; acc[3]  += a * w0.w;
      acc[4]  += a * w1.x; acc[5]  += a * w1.y; acc[6]  += a * w1.z; acc[7]  += a * w1.w;
      acc[8]  += a * w2.x; acc[9]  += a * w2.y; acc[10] += a * w2.z; acc[11] += a * w2.w;
      acc[12] += a * w3.x; acc[13] += a * w3.y; acc[14] += a * w3.z; acc[15] += a * w3.w;
    }
  }

  if (mat < 2) {
    unsigned short* dst = (unsigned short*)(ws + (mat == 0 ? P_QH : P_KH));
    const float sc = (mat == 0) ? scale_s[cs >> 5] : 1.f;
    uint4 w0, w1;
    w0.x = pk_f16(acc[0]*sc,  acc[1]*sc);  w0.y = pk_f16(acc[2]*sc,  acc[3]*sc);
    w0.z = pk_f16(acc[4]*sc,  acc[5]*sc);  w0.w = pk_f16(acc[6]*sc,  acc[7]*sc);
    w1.x = pk_f16(acc[8]*sc,  acc[9]*sc);  w1.y = pk_f16(acc[10]*sc, acc[11]*sc);
    w1.z = pk_f16(acc[12]*sc, acc[13]*sc); w1.w = pk_f16(acc[14]*sc, acc[15]*sc);
    *(uint4*)(dst + (size_t)(r0 + rr) * 128 + cs)     = w0;
    *(uint4*)(dst + (size_t)(r0 + rr) * 128 + cs + 8) = w1;
  } else {
#pragma unroll
    for (int e = 0; e < 16; ++e) o_s[rr][cs + e] = acc[e];
    __syncthreads();
    unsigned short* vt = (unsigned short*)(ws + P_VT);
    const int c = t >> 1, rb = (t & 1) << 4;
    float v[16];
#pragma unroll
    for (int mm = 0; mm < 16; ++mm) v[mm] = o_s[rb + mm][c];
    uint4 w0, w1;
    w0.x = pk_f16(v[0],  v[1]);  w0.y = pk_f16(v[2],  v[3]);
    w0.z = pk_f16(v[4],  v[5]);  w0.w = pk_f16(v[6],  v[7]);
    w1.x = pk_f16(v[8],  v[9]);  w1.y = pk_f16(v[10], v[11]);
    w1.z = pk_f16(v[12], v[13]); w1.w = pk_f16(v[14], v[15]);
    *(uint4*)(vt + (size_t)c * 4096 + r0 + rb)     = w0;
    *(uint4*)(vt + (size_t)c * 4096 + r0 + rb + 8) = w1;
  }
}

// ---------------- k4: fused masked flash attention (fp16 MFMA) ----------------
// wave w = head w; 32 i-rows/block; pipelined K/V/stf loads; exact defer-max.
__global__ __launch_bounds__(256, 4) void k4_attn(
    const float* __restrict__ adj, const float* __restrict__ trig,
    const float* __restrict__ stb, float* __restrict__ ws)
{
  __shared__ float adj_s[2][BI][36];  // padded
  const int tid = threadIdx.x;
  const int w = tid >> 6, l = tid & 63, li = l & 15, g = l >> 4;
  const int i0 = blockIdx.x * BI;
  const int jbeg = blockIdx.y * JCHUNK;
  const _Float16* Qh = (const _Float16*)(ws + P_QH);
  const _Float16* Kh = (const _Float16*)(ws + P_KH);
  const _Float16* VT = (const _Float16*)(ws + P_VT);
  const float* stf = ws + P_STF;
  const float stb_eff = stb[w] * (1.f - trig[0]) * LOG2E;

  f16x8 qf[2];
  float a_stb[2], m[2], pls[2];
  f32x4 agg[2][2];
#pragma unroll
  for (int it = 0; it < 2; ++it) {
    qf[it] = *(const f16x8*)(Qh + (size_t)(i0 + it*16 + li) * 128 + w * 32 + g * 8);
    a_stb[it] = stf[i0 + it*16 + li] * stb_eff;
    m[it] = -1e30f; pls[it] = 0.f;
    agg[it][0] = (f32x4){0.f, 0.f, 0.f, 0.f};
    agg[it][1] = (f32x4){0.f, 0.f, 0.f, 0.f};
  }

  const int sr = tid >> 3, sjb = (tid & 7) << 2;   // 32 rows x 8 float4
  const float* adj_base = adj + (size_t)(i0 + sr) * 4096 + jbeg + sjb;

  // pipelined frag sets A/B
  f16x8 kf0A, kf1A, kf0B, kf1B;
  uint2 vaA, vbA, vcA, vdA, vaB, vbB, vcB, vdB;
  f32x4 st0A, st1A, st0B, st1B;

#define LOADF(jtv, S) do { \
    kf0##S = *(const f16x8*)(Kh + (size_t)((jtv) + li) * 128 + w * 32 + g * 8); \
    kf1##S = *(const f16x8*)(Kh + (size_t)((jtv) + 16 + li) * 128 + w * 32 + g * 8); \
    const _Float16* vr_ = VT + (size_t)(w * 32 + li) * 4096 + (jtv) + g * 4; \
    va##S = *(const uint2*)vr_;                 vb##S = *(const uint2*)(vr_ + 16); \
    vc##S = *(const uint2*)(vr_ + 16*4096);     vd##S = *(const uint2*)(vr_ + 16*4096 + 16); \
    st0##S = *(const f32x4*)(stf + (jtv) + g * 4); \
    st1##S = *(const f32x4*)(stf + (jtv) + 16 + g * 4); \
  } while (0)

  auto compute = [&](const f16x8& kf0, const f16x8& kf1,
                     const uint2& va, const uint2& vb, const uint2& vc, const uint2& vd,
                     const f32x4& st0, const f32x4& st1, int buf) {
    union { unsigned u[4]; f16x8 h; } vf0, vf1;
    vf0.u[0] = va.x; vf0.u[1] = va.y; vf0.u[2] = vb.x; vf0.u[3] = vb.y;
    vf1.u[0] = vc.x; vf1.u[1] = vc.y; vf1.u[2] = vd.x; vf1.u[3] = vd.y;
#pragma unroll
    for (int it = 0; it < 2; ++it) {
      const f32x4 zero = {0.f, 0.f, 0.f, 0.f};
      f32x4 c0 = __builtin_amdgcn_mfma_f32_16x16x32_f16(kf0, qf[it], zero, 0, 0, 0);
      f32x4 c1 = __builtin_amdgcn_mfma_f32_16x16x32_f16(kf1, qf[it], zero, 0, 0, 0);
      const f32x4 ad0 = *(const f32x4*)&adj_s[buf][it*16 + li][g * 4];
      const f32x4 ad1 = *(const f32x4*)&adj_s[buf][it*16 + li][16 + g * 4];
      float s0[4], s1[4];
#pragma unroll
      for (int e = 0; e < 4; ++e) {
        s0[e] = ((ad0[e] == 0.f) ? -1e9f : c0[e]) + a_stb[it] * st0[e];
        s1[e] = ((ad1[e] == 0.f) ? -1e9f : c1[e]) + a_stb[it] * st1[e];
      }
      const float pl = fmaxf(fmaxf(fmaxf(s0[0], s0[1]), fmaxf(s0[2], s0[3])),
                             fmaxf(fmaxf(s1[0], s1[1]), fmaxf(s1[2], s1[3])));
      if (!__all(pl <= m[it])) {   // exact defer-max: skip reduce+rescale when no growth
        float mx = fmaxf(pl, __shfl_xor(pl, 16));
        mx = fmaxf(mx, __shfl_xor(mx, 32));
        const float mn = fmaxf(m[it], mx);
        const float f = exp2f(m[it] - mn);
        m[it] = mn;
        pls[it] *= f;
#pragma unroll
        for (int e = 0; e < 4; ++e) { agg[it][0][e] *= f; agg[it][1][e] *= f; }
      }
      float p0[4], p1[4];
#pragma unroll
      for (int e = 0; e < 4; ++e) { p0[e] = exp2f(s0[e] - m[it]); p1[e] = exp2f(s1[e] - m[it]); }
      pls[it] += ((p0[0] + p0[1]) + (p0[2] + p0[3])) + ((p1[0] + p1[1]) + (p1[2] + p1[3]));
      union { unsigned u[4]; f16x8 h; } pb;
      pb.u[0] = pk_f16(p0[0], p0[1]);
      pb.u[1] = pk_f16(p0[2], p0[3]);
      pb.u[2] = pk_f16(p1[0], p1[1]);
      pb.u[3] = pk_f16(p1[2], p1[3]);
      agg[it][0] = __builtin_amdgcn_mfma_f32_16x16x32_f16(vf0.h, pb.h, agg[it][0], 0, 0, 0);
      agg[it][1] = __builtin_amdgcn_mfma_f32_16x16x32_f16(vf1.h, pb.h, agg[it][1], 0, 0, 0);
    }
  };

  f32x4 rg = __builtin_nontemporal_load((const f32x4*)adj_base);   // t=0
  *(f32x4*)&adj_s[0][sr][sjb] = rg;
  LOADF(jbeg, A);

  for (int t = 0; t < NT; t += 2) {
    // ---- even tile t (buf 0)
    rg = __builtin_nontemporal_load((const f32x4*)(adj_base + (t + 1) * 32));
    __syncthreads();
    LOADF(jbeg + (t + 1) * 32, B);
    compute(kf0A, kf1A, vaA, vbA, vcA, vdA, st0A, st1A, 0);
    *(f32x4*)&adj_s[1][sr][sjb] = rg;
    // ---- odd tile t+1 (buf 1)
    if (t + 2 < NT)
      rg = __builtin_nontemporal_load((const f32x4*)(adj_base + (t + 2) * 32));
    __syncthreads();
    if (t + 2 < NT) LOADF(jbeg + (t + 2) * 32, A);
    compute(kf0B, kf1B, vaB, vbB, vcB, vdB, st0B, st1B, 1);
    if (t + 2 < NT) *(f32x4*)&adj_s[0][sr][sjb] = rg;
  }
#undef LOADF

  // partials: agg^T lane layout: d_local = 16*db + 4g + e, i = i0 + it*16 + li
#pragma unroll
  for (int it = 0; it < 2; ++it) {
    float ls = pls[it];
    ls += __shfl_xor(ls, 16);
    ls += __shfl_xor(ls, 32);
    float* pagg = ws + P_PAGG + ((size_t)(blockIdx.y * 4 + w) * 4096 + (i0 + it*16 + li)) * 32;
    *(f32x4*)(pagg + g * 4)      = agg[it][0];
    *(f32x4*)(pagg + 16 + g * 4) = agg[it][1];
    if (g == 0) {
      float* pml = ws + P_PML + ((size_t)(blockIdx.y * 4 + w) * 4096 + (i0 + it*16 + li)) * 2;
      pml[0] = m[it];
      pml[1] = ls;
    }
  }
}

// ---------------- k5: combine + Wo GEMM (k-split staging) + LN2 + residual ----------------
__global__ __launch_bounds__(256) void k5_out(
    const float* __restrict__ Wo, const float* __restrict__ bo,
    const float* __restrict__ g2, const float* __restrict__ b2,
    const float* __restrict__ res_scale,
    const float* __restrict__ trig, const float* __restrict__ Wg,
    const float* __restrict__ bg,
    float* __restrict__ ws, float* __restrict__ out)
{
  __shared__ float wo_s[64][128];  // Wo^T half: [k][c], staged twice (32 KB)
  __shared__ float agg_s[16][132];
  __shared__ float red[16][16][2];
  __shared__ float mu_s[16], rs_s[16];
  __shared__ float gate_red[2];
  const int t = threadIdx.x;
  const int i0 = blockIdx.x * 16;

  if (t < 128) { // inline gate = mean(sigmoid(Wg@trig + bg))
    float gx = bg[t] + trig[0] * Wg[t*3+0] + trig[1] * Wg[t*3+1] + trig[2] * Wg[t*3+2];
    float gs = 1.f / (1.f + __expf(-gx));
    for (int off = 1; off < 64; off <<= 1) gs += __shfl_xor(gs, off);
    if ((t & 63) == 0) gate_red[t >> 6] = gs;
  }
  __syncthreads();
  const float gate = (gate_red[0] + gate_red[1]) * (1.f / 128.f);

  { // combine j-split partials -> agg_s (gate * sum(pV)/l)
    const int hd = t & 127, ih = t >> 7;
    const int h = hd >> 5, d = hd & 31;
    for (int ir = 0; ir < 8; ++ir) {
      const int il = ih * 8 + ir;
      const int i = i0 + il;
      float mv[JSPLIT], lv[JSPLIT];
      float mm = -1e30f;
#pragma unroll
      for (int sp = 0; sp < JSPLIT; ++sp) {
        const float* ml = ws + P_PML + ((size_t)(sp * 4 + h) * 4096 + i) * 2;
        mv[sp] = ml[0]; lv[sp] = ml[1];
        mm = fmaxf(mm, mv[sp]);
      }
      float lt = 0.f, av = 0.f;
#pragma unroll
      for (int sp = 0; sp < JSPLIT; ++sp) {
        const float wgt = exp2f(mv[sp] - mm);
        lt += lv[sp] * wgt;
        av += ws[P_PAGG + ((size_t)(sp * 4 + h) * 4096 + i) * 32 + d] * wgt;
      }
      agg_s[il][hd] = av * gate / lt;
    }
  }

  const int r = t & 15, cs = (t >> 4) << 3;
  float acc[8];
#pragma unroll
  for (int e = 0; e < 8; ++e) acc[e] = bo[cs + e];

  for (int kh = 0; kh < 2; ++kh) {
    __syncthreads();   // protect wo_s reuse (and covers agg_s on first pass)
    { // stage Wo^T[kh*64 + kk][c] into wo_s[kk][c]
      const int c = t >> 1, kb = (t & 1) << 5;
      const float4* src = (const float4*)(Wo + c * 128 + kh * 64 + kb);
#pragma unroll
      for (int q = 0; q < 8; ++q) {
        float4 v = src[q];
        wo_s[kb + 4*q + 0][c] = v.x; wo_s[kb + 4*q + 1][c] = v.y;
        wo_s[kb + 4*q + 2][c] = v.z; wo_s[kb + 4*q + 3][c] = v.w;
      }
    }
    __syncthreads();
    for (int k = 0; k < 64; ++k) {
      const float a = agg_s[r][kh * 64 + k];
      const float4 w0 = *(const float4*)&wo_s[k][cs];
      const float4 w1 = *(const float4*)&wo_s[k][cs + 4];
      acc[0] += a * w0.x; acc[1] += a * w0.y; acc[2] += a * w0.z; acc[3] += a * w0.w;
      acc[4] += a * w1.x; acc[5] += a * w1.y; acc[6] += a * w1.z; acc[7] += a * w1.w;
    }
  }

  float s = 0.f, sq = 0.f;
#pragma unroll
  for (int e = 0; e < 8; ++e) { s += acc[e]; sq += acc[e] * acc[e]; }
  red[r][t >> 4][0] = s; red[r][t >> 4][1] = sq;
  __syncthreads();
  if (t < 16) {
    float ss = 0.f, qq = 0.f;
    for (int q = 0; q < 16; ++q) { ss += red[t][q][0]; qq += red[t][q][1]; }
    const float mu = ss * (1.f / 128.f);
    const float var = qq * (1.f / 128.f) - mu * mu;
    mu_s[t] = mu; rs_s[t] = rsqrtf(var + 1e-5f);
  }
  __syncthreads();
  const float mu = mu_s[r], rs = rs_s[r];
  const float rsc = res_scale[0];
  const float* hrow = ws + P_H + (size_t)(i0 + r) * 128 + cs;
  const float4 h0 = *(const float4*)(hrow), h1 = *(const float4*)(hrow + 4);
  const float4 ga = *(const float4*)(g2 + cs), gb = *(const float4*)(g2 + cs + 4);
  const float4 ba = *(const float4*)(b2 + cs), bb = *(const float4*)(b2 + cs + 4);
  float4 o0, o1;
  o0.x = (acc[0] - mu) * rs * ga.x + ba.x + rsc * h0.x;
  o0.y = (acc[1] - mu) * rs * ga.y + ba.y + rsc * h0.y;
  o0.z = (acc[2] - mu) * rs * ga.z + ba.z + rsc * h0.z;
  o0.w = (acc[3] - mu) * rs * ga.w + ba.w + rsc * h0.w;
  o1.x = (acc[4] - mu) * rs * gb.x + bb.x + rsc * h1.x;
  o1.y = (acc[5] - mu) * rs * gb.y + bb.y + rsc * h1.y;
  o1.z = (acc[6] - mu) * rs * gb.z + bb.z + rsc * h1.z;
  o1.w = (acc[7] - mu) * rs * gb.w + bb.w + rsc * h1.w;
  *(float4*)(out + (size_t)(i0 + r) * 128 + cs)     = o0;
  *(float4*)(out + (size_t)(i0 + r) * 128 + cs + 4) = o1;
}

extern "C" void kernel_launch(void* const* d_in, const int* in_sizes, int n_in,
                              void* d_out, int out_size, void* d_ws, size_t ws_size,
                              hipStream_t stream) {
  const float* nf   = (const float*)d_in[0];
  const float* adj  = (const float*)d_in[1];
  const float* trig = (const float*)d_in[2];
  const float* Wp   = (const float*)d_in[3];
  const float* bp   = (const float*)d_in[4];
  const float* ln1g = (const float*)d_in[5];
  const float* ln1b = (const float*)d_in[6];
  const float* Wq   = (const float*)d_in[7];
  const float* Wk   = (const float*)d_in[8];
  const float* Wv   = (const float*)d_in[9];
  const float* Wt1  = (const float*)d_in[10];
  const float* bt1  = (const float*)d_in[11];
  const float* Wt2  = (const float*)d_in[12];
  const float* bt2  = (const float*)d_in[13];
  const float* Wg   = (const float*)d_in[14];
  const float* bg   = (const float*)d_in[15];
  const float* stb  = (const float*)d_in[16];
  const float* Wo   = (const float*)d_in[17];
  const float* bo   = (const float*)d_in[18];
  const float* ln2g = (const float*)d_in[19];
  const float* ln2b = (const float*)d_in[20];
  const float* rsc  = (const float*)d_in[21];
  float* ws  = (float*)d_ws;
  float* out = (float*)d_out;

  hipLaunchKernelGGL(k2_h, dim3(NNODES), dim3(128), 0, stream, nf, trig, Wp, bp, ln1g, ln1b, ws);
  hipLaunchKernelGGL(k3_qkv, dim3(128, 3), dim3(256), 0, stream,
                     Wq, Wk, Wv, trig, Wt1, bt1, Wt2, bt2, ws);
  hipLaunchKernelGGL(k4_attn, dim3(NNODES / BI, JSPLIT), dim3(256), 0, stream, adj, trig, stb, ws);
  hipLaunchKernelGGL(k5_out, dim3(256), dim3(256), 0, stream,
                     Wo, bo, ln2g, ln2b, rsc, trig, Wg, bg, ws, out);
}

// Round 9
// 208.321 us; speedup vs baseline: 1.1079x; 1.0981x over previous
//
#include <hip/hip_runtime.h>

// TriggerAwareGAT fused pipeline for MI355X (gfx950).
// k2: h = relu(LN1(enriched@Wp^T+bp)) + inline c_trig        [4096 x 128]
// k3: Q (fp16, scaled), K/V in MFMA-fragment-packed fp16     [128x3 x 256]
// k4: flash masked attention, fp16 MFMA, dense 1KB/wave frag loads,
//     pipelined, exact defer-max, j-split=8                   [128x8 x 256]
// k5: combine partials + inline gate, Wo GEMM, LN2, residual  [256 x 256]

#define NNODES 4096
#define BI     32                    // i-rows per k4 block
#define JSPLIT 8
#define JCHUNK (NNODES / JSPLIT)     // 512
#define NT     (JCHUNK / 32)         // 16

typedef float    f32x4 __attribute__((ext_vector_type(4)));
typedef _Float16 f16x8 __attribute__((ext_vector_type(8)));
typedef __fp16   fp16x2 __attribute__((ext_vector_type(2)));

// workspace layout (float offsets)
#define P_STF    256
#define P_H      4352
#define P_QH     528640
#define P_KH     790784   // KP: [4 heads][128 tiles][2 pairs][64 lanes][8 halves]
#define P_VT     1052928  // VP: same fragment-packed layout
#define P_PAGG   1315072  // [JSPLIT*4][4096][32] f32
#define P_PML    5509376  // [JSPLIT*4][4096][2]  f32

#define LOG2E 1.4426950408889634f

__device__ __forceinline__ unsigned pk_f16(float lo, float hi) {
  union { fp16x2 h; unsigned u; } c;
  c.h = __builtin_amdgcn_cvt_pkrtz(lo, hi);
  return c.u;
}

// ---------------- k2: h = relu(LN1(enriched@Wp^T + bp)) ----------------
__global__ __launch_bounds__(128) void k2_h(
    const float* __restrict__ nf, const float* __restrict__ trig,
    const float* __restrict__ Wp, const float* __restrict__ bp,
    const float* __restrict__ g, const float* __restrict__ b,
    float* __restrict__ ws)
{
  const int i = blockIdx.x, j = threadIdx.x; // 128 threads / row
  const float t0 = trig[0], t1v = trig[1], t2 = trig[2];
  const float n0 = nf[i*3+0], n1 = nf[i*3+1], n2 = nf[i*3+2];
  const float* wr = Wp + j * 6;
  const float x = bp[j] + n0 * wr[0] + n1 * wr[1] + n2 * wr[2]
                        + t0 * wr[3] + t1v * wr[4] + t2 * wr[5];
  float s = x, sq = x * x;
  for (int off = 1; off < 64; off <<= 1) { s += __shfl_xor(s, off); sq += __shfl_xor(sq, off); }
  __shared__ float red[2][2];
  if ((j & 63) == 0) { red[j >> 6][0] = s; red[j >> 6][1] = sq; }
  __syncthreads();
  const float mu = (red[0][0] + red[1][0]) * (1.f / 128.f);
  const float var = (red[0][1] + red[1][1]) * (1.f / 128.f) - mu * mu;
  const float rs = rsqrtf(var + 1e-5f);
  const float hv = fmaxf((x - mu) * rs * g[j] + b[j], 0.f);
  ws[P_H + (size_t)i * 128 + j] = hv;
  if (j == 0) ws[P_STF + i] = n2;   // is_stateful
}

// ---------------- k3: QKV GEMMs -> fp16 Q (scaled) + fragment-packed K,V ----------------
__global__ __launch_bounds__(256) void k3_qkv(
    const float* __restrict__ Wq, const float* __restrict__ Wk,
    const float* __restrict__ Wv, const float* __restrict__ trig,
    const float* __restrict__ Wt1, const float* __restrict__ bt1,
    const float* __restrict__ Wt2, const float* __restrict__ bt2,
    float* __restrict__ ws)
{
  __shared__ float h_s[32][129];
  __shared__ float w_s[32][128];   // W^T chunk [k][c]
  __shared__ float o_s[32][132];   // V tile buffer [j][d]
  __shared__ float t1_s[64];
  __shared__ float scale_s[4];
  const int t = threadIdx.x;
  const int r0 = blockIdx.x * 32;
  const int mat = blockIdx.y;
  const float* W = (mat == 0) ? Wq : (mat == 1) ? Wk : Wv;
  const float* hp = ws + P_H;

  { // stage h tile
    const int r = t >> 3, kb = (t & 7) << 4;
    const float4* src = (const float4*)(hp + (size_t)(r0 + r) * 128 + kb);
#pragma unroll
    for (int p = 0; p < 4; ++p) {
      float4 v = src[p];
      h_s[r][kb + 4*p + 0] = v.x; h_s[r][kb + 4*p + 1] = v.y;
      h_s[r][kb + 4*p + 2] = v.z; h_s[r][kb + 4*p + 3] = v.w;
    }
  }
  if (t < 64) { // trigger hidden layer (for temp/scale, used by mat==0 only)
    float a = bt1[t] + trig[0] * Wt1[t*3+0] + trig[1] * Wt1[t*3+1] + trig[2] * Wt1[t*3+2];
    t1_s[t] = fmaxf(a, 0.f);
  }
  __syncthreads();
  if (t < 4) {
    float acc = bt2[t];
    for (int k = 0; k < 64; ++k) acc += Wt2[t*64+k] * t1_s[k];
    float sp = (acc > 20.f) ? acc : log1pf(__expf(acc));
    float temp = fminf(fmaxf(sp, 0.1f), 5.f);
    scale_s[t] = LOG2E / (5.656854249492380f * temp); // log2e/(sqrt(32)*temp)
  }

  const int rr = t & 31, cs = (t >> 5) << 4;
  float acc[16];
#pragma unroll
  for (int e = 0; e < 16; ++e) acc[e] = 0.f;

  for (int kc = 0; kc < 4; ++kc) {
    __syncthreads();
    { // stage W^T chunk (transposed in LDS so compute reads are conflict-free)
      const int c = t >> 1, kk = (t & 1) << 4;
      const float4* srcw = (const float4*)(W + c * 128 + kc * 32 + kk);
#pragma unroll
      for (int p = 0; p < 4; ++p) {
        float4 v = srcw[p];
        w_s[kk + 4*p + 0][c] = v.x; w_s[kk + 4*p + 1][c] = v.y;
        w_s[kk + 4*p + 2][c] = v.z; w_s[kk + 4*p + 3][c] = v.w;
      }
    }
    __syncthreads();
#pragma unroll
    for (int k = 0; k < 32; ++k) {
      const float a = h_s[rr][kc * 32 + k];
      const float4 w0 = *(const float4*)&w_s[k][cs + 0];
      const float4 w1 = *(const float4*)&w_s[k][cs + 4];
      const float4 w2 = *(const float4*)&w_s[k][cs + 8];
      const float4 w3 = *(const float4*)&w_s[k][cs + 12];
      acc[0]  += a * w0.x; acc[1]  += a * w0.y; acc[2]  += a * w0.z; acc[3]  += a * w0.w;
      acc[4]  += a * w1.x; acc[5]  += a * w1.y; acc[6]  += a * w1.z; acc[7]  += a * w1.w;
      acc[8]  += a * w2.x; acc[9]  += a * w2.y; acc[10] += a * w2.z; acc[11] += a * w2.w;
      acc[12] += a * w3.x; acc[13] += a * w3.y; acc[14] += a * w3.z; acc[15] += a * w3.w;
    }
  }

  const int tile = r0 >> 5;
  if (mat == 0) {
    unsigned short* dst = (unsigned short*)(ws + P_QH);
    const float sc = scale_s[cs >> 5];
    uint4 w0, w1;
    w0.x = pk_f16(acc[0]*sc,  acc[1]*sc);  w0.y = pk_f16(acc[2]*sc,  acc[3]*sc);
    w0.z = pk_f16(acc[4]*sc,  acc[5]*sc);  w0.w = pk_f16(acc[6]*sc,  acc[7]*sc);
    w1.x = pk_f16(acc[8]*sc,  acc[9]*sc);  w1.y = pk_f16(acc[10]*sc, acc[11]*sc);
    w1.z = pk_f16(acc[12]*sc, acc[13]*sc); w1.w = pk_f16(acc[14]*sc, acc[15]*sc);
    *(uint4*)(dst + (size_t)(r0 + rr) * 128 + cs)     = w0;
    *(uint4*)(dst + (size_t)(r0 + rr) * 128 + cs + 8) = w1;
  } else if (mat == 1) {
    // K -> fragment-packed: KP[head][tile][pair][lane l=g*16+li][8 halves]
    unsigned short* kp = (unsigned short*)(ws + P_KH);
    const int li = rr & 15, pair = rr >> 4;
    const int head = cs >> 5, g0 = (cs & 31) >> 3;   // this thread covers g0, g0+1
    uint4 w0, w1;
    w0.x = pk_f16(acc[0],  acc[1]);  w0.y = pk_f16(acc[2],  acc[3]);
    w0.z = pk_f16(acc[4],  acc[5]);  w0.w = pk_f16(acc[6],  acc[7]);
    w1.x = pk_f16(acc[8],  acc[9]);  w1.y = pk_f16(acc[10], acc[11]);
    w1.z = pk_f16(acc[12], acc[13]); w1.w = pk_f16(acc[14], acc[15]);
    const size_t base = ((size_t)((head * 128 + tile) * 2 + pair)) * 64;
    *(uint4*)(kp + (base + (g0 * 16 + li)) * 8)       = w0;
    *(uint4*)(kp + (base + ((g0 + 1) * 16 + li)) * 8) = w1;
  } else {
    // V -> fragment-packed VP matching PV k-slot order
#pragma unroll
    for (int e = 0; e < 16; ++e) o_s[rr][cs + e] = acc[e];
    __syncthreads();
    unsigned short* vp = (unsigned short*)(ws + P_VT);
#pragma unroll
    for (int q = 0; q < 2; ++q) {
      const int f = t + q * 256;              // fragment id 0..511
      const int head = f >> 7, rem = f & 127, pair = rem >> 6, l = rem & 63;
      const int g = l >> 4, li = l & 15;
      const int d = head * 32 + pair * 16 + li;
      uint4 wv;
      wv.x = pk_f16(o_s[4*g + 0][d],      o_s[4*g + 1][d]);
      wv.y = pk_f16(o_s[4*g + 2][d],      o_s[4*g + 3][d]);
      wv.z = pk_f16(o_s[16 + 4*g + 0][d], o_s[16 + 4*g + 1][d]);
      wv.w = pk_f16(o_s[16 + 4*g + 2][d], o_s[16 + 4*g + 3][d]);
      *(uint4*)(vp + (((size_t)((head * 128 + tile) * 2 + pair)) * 64 + l) * 8) = wv;
    }
  }
}

// ---------------- k4: fused masked flash attention (fp16 MFMA) ----------------
// wave w = head w; 32 i-rows/block; dense fragment loads; exact defer-max.
__global__ __launch_bounds__(256, 4) void k4_attn(
    const float* __restrict__ adj, const float* __restrict__ trig,
    const float* __restrict__ stb, float* __restrict__ ws)
{
  __shared__ float adj_s[2][BI][36];  // padded
  const int tid = threadIdx.x;
  const int w = tid >> 6, l = tid & 63, li = l & 15, g = l >> 4;
  const int i0 = blockIdx.x * BI;
  const int jbeg = blockIdx.y * JCHUNK;
  const int tbeg = jbeg >> 5;
  const _Float16* Qh = (const _Float16*)(ws + P_QH);
  const _Float16* KP = (const _Float16*)(ws + P_KH);
  const _Float16* VP = (const _Float16*)(ws + P_VT);
  const float* stf = ws + P_STF;
  const float stb_eff = stb[w] * (1.f - trig[0]) * LOG2E;

  f16x8 qf[2];
  float a_stb[2], m[2], pls[2];
  f32x4 agg[2][2];
#pragma unroll
  for (int it = 0; it < 2; ++it) {
    qf[it] = *(const f16x8*)(Qh + (size_t)(i0 + it*16 + li) * 128 + w * 32 + g * 8);
    a_stb[it] = stf[i0 + it*16 + li] * stb_eff;
    m[it] = -1e30f; pls[it] = 0.f;
    agg[it][0] = (f32x4){0.f, 0.f, 0.f, 0.f};
    agg[it][1] = (f32x4){0.f, 0.f, 0.f, 0.f};
  }

  const int sr = tid >> 3, sjb = (tid & 7) << 2;   // 32 rows x 8 float4
  const float* adj_base = adj + (size_t)(i0 + sr) * 4096 + jbeg + sjb;
  const int l8 = l * 8;

  // pipelined frag sets A/B (dense 16B loads from fragment-packed KP/VP)
  f16x8 kf0A, kf1A, kf0B, kf1B, vf0A, vf1A, vf0B, vf1B;
  f32x4 st0A, st1A, st0B, st1B;

#define LOADF(tg, S) do { \
    const size_t kb = ((size_t)(w * 128 + (tg))) * 1024 + l8; \
    kf0##S = *(const f16x8*)(KP + kb); \
    kf1##S = *(const f16x8*)(KP + kb + 512); \
    vf0##S = *(const f16x8*)(VP + kb); \
    vf1##S = *(const f16x8*)(VP + kb + 512); \
    st0##S = *(const f32x4*)(stf + (tg) * 32 + g * 4); \
    st1##S = *(const f32x4*)(stf + (tg) * 32 + 16 + g * 4); \
  } while (0)

  auto compute = [&](const f16x8& kf0, const f16x8& kf1,
                     const f16x8& vf0, const f16x8& vf1,
                     const f32x4& st0, const f32x4& st1, int buf) {
#pragma unroll
    for (int it = 0; it < 2; ++it) {
      const f32x4 zero = {0.f, 0.f, 0.f, 0.f};
      f32x4 c0 = __builtin_amdgcn_mfma_f32_16x16x32_f16(kf0, qf[it], zero, 0, 0, 0);
      f32x4 c1 = __builtin_amdgcn_mfma_f32_16x16x32_f16(kf1, qf[it], zero, 0, 0, 0);
      const f32x4 ad0 = *(const f32x4*)&adj_s[buf][it*16 + li][g * 4];
      const f32x4 ad1 = *(const f32x4*)&adj_s[buf][it*16 + li][16 + g * 4];
      float s0[4], s1[4];
#pragma unroll
      for (int e = 0; e < 4; ++e) {
        s0[e] = ((ad0[e] == 0.f) ? -1e9f : c0[e]) + a_stb[it] * st0[e];
        s1[e] = ((ad1[e] == 0.f) ? -1e9f : c1[e]) + a_stb[it] * st1[e];
      }
      const float pl = fmaxf(fmaxf(fmaxf(s0[0], s0[1]), fmaxf(s0[2], s0[3])),
                             fmaxf(fmaxf(s1[0], s1[1]), fmaxf(s1[2], s1[3])));
      if (!__all(pl <= m[it])) {   // exact defer-max
        float mx = fmaxf(pl, __shfl_xor(pl, 16));
        mx = fmaxf(mx, __shfl_xor(mx, 32));
        const float mn = fmaxf(m[it], mx);
        const float f = exp2f(m[it] - mn);
        m[it] = mn;
        pls[it] *= f;
#pragma unroll
        for (int e = 0; e < 4; ++e) { agg[it][0][e] *= f; agg[it][1][e] *= f; }
      }
      float p0[4], p1[4];
#pragma unroll
      for (int e = 0; e < 4; ++e) { p0[e] = exp2f(s0[e] - m[it]); p1[e] = exp2f(s1[e] - m[it]); }
      pls[it] += ((p0[0] + p0[1]) + (p0[2] + p0[3])) + ((p1[0] + p1[1]) + (p1[2] + p1[3]));
      union { unsigned u[4]; f16x8 h; } pb;
      pb.u[0] = pk_f16(p0[0], p0[1]);
      pb.u[1] = pk_f16(p0[2], p0[3]);
      pb.u[2] = pk_f16(p1[0], p1[1]);
      pb.u[3] = pk_f16(p1[2], p1[3]);
      agg[it][0] = __builtin_amdgcn_mfma_f32_16x16x32_f16(vf0, pb.h, agg[it][0], 0, 0, 0);
      agg[it][1] = __builtin_amdgcn_mfma_f32_16x16x32_f16(vf1, pb.h, agg[it][1], 0, 0, 0);
    }
  };

  f32x4 rg = __builtin_nontemporal_load((const f32x4*)adj_base);   // t=0
  *(f32x4*)&adj_s[0][sr][sjb] = rg;
  LOADF(tbeg, A);

  for (int t = 0; t < NT; t += 2) {
    // ---- even tile t (buf 0)
    rg = __builtin_nontemporal_load((const f32x4*)(adj_base + (t + 1) * 32));
    __syncthreads();
    LOADF(tbeg + t + 1, B);
    compute(kf0A, kf1A, vf0A, vf1A, st0A, st1A, 0);
    *(f32x4*)&adj_s[1][sr][sjb] = rg;
    // ---- odd tile t+1 (buf 1)
    if (t + 2 < NT)
      rg = __builtin_nontemporal_load((const f32x4*)(adj_base + (t + 2) * 32));
    __syncthreads();
    if (t + 2 < NT) LOADF(tbeg + t + 2, A);
    compute(kf0B, kf1B, vf0B, vf1B, st0B, st1B, 1);
    if (t + 2 < NT) *(f32x4*)&adj_s[0][sr][sjb] = rg;
  }
#undef LOADF

  // partials: agg^T lane layout: d_local = 16*db + 4g + e, i = i0 + it*16 + li
#pragma unroll
  for (int it = 0; it < 2; ++it) {
    float ls = pls[it];
    ls += __shfl_xor(ls, 16);
    ls += __shfl_xor(ls, 32);
    float* pagg = ws + P_PAGG + ((size_t)(blockIdx.y * 4 + w) * 4096 + (i0 + it*16 + li)) * 32;
    *(f32x4*)(pagg + g * 4)      = agg[it][0];
    *(f32x4*)(pagg + 16 + g * 4) = agg[it][1];
    if (g == 0) {
      float* pml = ws + P_PML + ((size_t)(blockIdx.y * 4 + w) * 4096 + (i0 + it*16 + li)) * 2;
      pml[0] = m[it];
      pml[1] = ls;
    }
  }
}

// ---------------- k5: combine + Wo GEMM (k-split staging) + LN2 + residual ----------------
__global__ __launch_bounds__(256) void k5_out(
    const float* __restrict__ Wo, const float* __restrict__ bo,
    const float* __restrict__ g2, const float* __restrict__ b2,
    const float* __restrict__ res_scale,
    const float* __restrict__ trig, const float* __restrict__ Wg,
    const float* __restrict__ bg,
    float* __restrict__ ws, float* __restrict__ out)
{
  __shared__ float wo_s[64][128];  // Wo^T half: [k][c], staged twice (32 KB)
  __shared__ float agg_s[16][132];
  __shared__ float red[16][16][2];
  __shared__ float mu_s[16], rs_s[16];
  __shared__ float gate_red[2];
  const int t = threadIdx.x;
  const int i0 = blockIdx.x * 16;

  if (t < 128) { // inline gate = mean(sigmoid(Wg@trig + bg))
    float gx = bg[t] + trig[0] * Wg[t*3+0] + trig[1] * Wg[t*3+1] + trig[2] * Wg[t*3+2];
    float gs = 1.f / (1.f + __expf(-gx));
    for (int off = 1; off < 64; off <<= 1) gs += __shfl_xor(gs, off);
    if ((t & 63) == 0) gate_red[t >> 6] = gs;
  }
  __syncthreads();
  const float gate = (gate_red[0] + gate_red[1]) * (1.f / 128.f);

  { // combine j-split partials -> agg_s (gate * sum(pV)/l)
    const int hd = t & 127, ih = t >> 7;
    const int h = hd >> 5, d = hd & 31;
    for (int ir = 0; ir < 8; ++ir) {
      const int il = ih * 8 + ir;
      const int i = i0 + il;
      float mv[JSPLIT], lv[JSPLIT];
      float mm = -1e30f;
#pragma unroll
      for (int sp = 0; sp < JSPLIT; ++sp) {
        const float* ml = ws + P_PML + ((size_t)(sp * 4 + h) * 4096 + i) * 2;
        mv[sp] = ml[0]; lv[sp] = ml[1];
        mm = fmaxf(mm, mv[sp]);
      }
      float lt = 0.f, av = 0.f;
#pragma unroll
      for (int sp = 0; sp < JSPLIT; ++sp) {
        const float wgt = exp2f(mv[sp] - mm);
        lt += lv[sp] * wgt;
        av += ws[P_PAGG + ((size_t)(sp * 4 + h) * 4096 + i) * 32 + d] * wgt;
      }
      agg_s[il][hd] = av * gate / lt;
    }
  }

  const int r = t & 15, cs = (t >> 4) << 3;
  float acc[8];
#pragma unroll
  for (int e = 0; e < 8; ++e) acc[e] = bo[cs + e];

  for (int kh = 0; kh < 2; ++kh) {
    __syncthreads();   // protect wo_s reuse (and covers agg_s on first pass)
    { // stage Wo^T[kh*64 + kk][c] into wo_s[kk][c]
      const int c = t >> 1, kb = (t & 1) << 5;
      const float4* src = (const float4*)(Wo + c * 128 + kh * 64 + kb);
#pragma unroll
      for (int q = 0; q < 8; ++q) {
        float4 v = src[q];
        wo_s[kb + 4*q + 0][c] = v.x; wo_s[kb + 4*q + 1][c] = v.y;
        wo_s[kb + 4*q + 2][c] = v.z; wo_s[kb + 4*q + 3][c] = v.w;
      }
    }
    __syncthreads();
    for (int k = 0; k < 64; ++k) {
      const float a = agg_s[r][kh * 64 + k];
      const float4 w0 = *(const float4*)&wo_s[k][cs];
      const float4 w1 = *(const float4*)&wo_s[k][cs + 4];
      acc[0] += a * w0.x; acc[1] += a * w0.y; acc[2] += a * w0.z; acc[3] += a * w0.w;
      acc[4] += a * w1.x; acc[5] += a * w1.y; acc[6] += a * w1.z; acc[7] += a * w1.w;
    }
  }

  float s = 0.f, sq = 0.f;
#pragma unroll
  for (int e = 0; e < 8; ++e) { s += acc[e]; sq += acc[e] * acc[e]; }
  red[r][t >> 4][0] = s; red[r][t >> 4][1] = sq;
  __syncthreads();
  if (t < 16) {
    float ss = 0.f, qq = 0.f;
    for (int q = 0; q < 16; ++q) { ss += red[t][q][0]; qq += red[t][q][1]; }
    const float mu = ss * (1.f / 128.f);
    const float var = qq * (1.f / 128.f) - mu * mu;
    mu_s[t] = mu; rs_s[t] = rsqrtf(var + 1e-5f);
  }
  __syncthreads();
  const float mu = mu_s[r], rs = rs_s[r];
  const float rsc = res_scale[0];
  const float* hrow = ws + P_H + (size_t)(i0 + r) * 128 + cs;
  const float4 h0 = *(const float4*)(hrow), h1 = *(const float4*)(hrow + 4);
  const float4 ga = *(const float4*)(g2 + cs), gb = *(const float4*)(g2 + cs + 4);
  const float4 ba = *(const float4*)(b2 + cs), bb = *(const float4*)(b2 + cs + 4);
  float4 o0, o1;
  o0.x = (acc[0] - mu) * rs * ga.x + ba.x + rsc * h0.x;
  o0.y = (acc[1] - mu) * rs * ga.y + ba.y + rsc * h0.y;
  o0.z = (acc[2] - mu) * rs * ga.z + ba.z + rsc * h0.z;
  o0.w = (acc[3] - mu) * rs * ga.w + ba.w + rsc * h0.w;
  o1.x = (acc[4] - mu) * rs * gb.x + bb.x + rsc * h1.x;
  o1.y = (acc[5] - mu) * rs * gb.y + bb.y + rsc * h1.y;
  o1.z = (acc[6] - mu) * rs * gb.z + bb.z + rsc * h1.z;
  o1.w = (acc[7] - mu) * rs * gb.w + bb.w + rsc * h1.w;
  *(float4*)(out + (size_t)(i0 + r) * 128 + cs)     = o0;
  *(float4*)(out + (size_t)(i0 + r) * 128 + cs + 4) = o1;
}

extern "C" void kernel_launch(void* const* d_in, const int* in_sizes, int n_in,
                              void* d_out, int out_size, void* d_ws, size_t ws_size,
                              hipStream_t stream) {
  const float* nf   = (const float*)d_in[0];
  const float* adj  = (const float*)d_in[1];
  const float* trig = (const float*)d_in[2];
  const float* Wp   = (const float*)d_in[3];
  const float* bp   = (const float*)d_in[4];
  const float* ln1g = (const float*)d_in[5];
  const float* ln1b = (const float*)d_in[6];
  const float* Wq   = (const float*)d_in[7];
  const float* Wk   = (const float*)d_in[8];
  const float* Wv   = (const float*)d_in[9];
  const float* Wt1  = (const float*)d_in[10];
  const float* bt1  = (const float*)d_in[11];
  const float* Wt2  = (const float*)d_in[12];
  const float* bt2  = (const float*)d_in[13];
  const float* Wg   = (const float*)d_in[14];
  const float* bg   = (const float*)d_in[15];
  const float* stb  = (const float*)d_in[16];
  const float* Wo   = (const float*)d_in[17];
  const float* bo   = (const float*)d_in[18];
  const float* ln2g = (const float*)d_in[19];
  const float* ln2b = (const float*)d_in[20];
  const float* rsc  = (const float*)d_in[21];
  float* ws  = (float*)d_ws;
  float* out = (float*)d_out;

  hipLaunchKernelGGL(k2_h, dim3(NNODES), dim3(128), 0, stream, nf, trig, Wp, bp, ln1g, ln1b, ws);
  hipLaunchKernelGGL(k3_qkv, dim3(128, 3), dim3(256), 0, stream,
                     Wq, Wk, Wv, trig, Wt1, bt1, Wt2, bt2, ws);
  hipLaunchKernelGGL(k4_attn, dim3(NNODES / BI, JSPLIT), dim3(256), 0, stream, adj, trig, stb, ws);
  hipLaunchKernelGGL(k5_out, dim3(256), dim3(256), 0, stream,
                     Wo, bo, ln2g, ln2b, rsc, trig, Wg, bg, ws, out);
}